// Round 8
// baseline (251.000 us; speedup 1.0000x reference)
//
#include <hip/hip_runtime.h>
#include <math.h>

#define NRREL 16
#define DDIM 128
#define BBATCH 4096
#define SNBR 64

typedef __attribute__((ext_vector_type(8))) short short8;
typedef __attribute__((ext_vector_type(4))) float floatx4;

__device__ __forceinline__ unsigned short f2bf(float f) {
    unsigned u = __builtin_bit_cast(unsigned, f);
    u += 0x7fffu + ((u >> 16) & 1u);
    return (unsigned short)(u >> 16);
}
__device__ __forceinline__ float bf2f(unsigned short u) {
    return __builtin_bit_cast(float, ((unsigned)u) << 16);
}

// ============ front: gather (blocks 0..4095) + weight conversion (4096..4351) =========
extern "C" __global__ __launch_bounds__(256)
void k_front(const int* __restrict__ drug, const int* __restrict__ adj_e,
             const int* __restrict__ adj_r, const float* __restrict__ ew,
             const float* __restrict__ emb, const float* __restrict__ W_rgcn,
             const float* __restrict__ res_w, const float* __restrict__ proj_w,
             const float* __restrict__ in_w, const float* __restrict__ out_w,
             unsigned short* __restrict__ pre_bf, float* __restrict__ node_f,
             unsigned short* __restrict__ Wcat, unsigned short* __restrict__ resw,
             unsigned short* __restrict__ projw, unsigned short* __restrict__ inw,
             unsigned short* __restrict__ outw)
{
    __shared__ union {
        struct {
            int memb[16][64];                   // relation bucket member lists
            int cnt[16];
            int sent[64];
            float swt[64];
        } g;
        struct { float tileT[64 * 65]; } w;
    } sm;

    const int bid = blockIdx.x, t = threadIdx.x;

    if (bid < BBATCH) {
        // ---------------- gather one batch row: direct global->register ----------------
        const int b = bid;
        if (t < 16) sm.g.cnt[t] = 0;
        __syncthreads();
        if (t < 64) {
            sm.g.sent[t] = adj_e[b * SNBR + t];
            sm.g.swt[t]  = ew[b * SNBR + t];
            int r = adj_r[b * SNBR + t];
            int slot = atomicAdd(&sm.g.cnt[r], 1);
            sm.g.memb[r][slot] = t;
        }
        if (t >= 64 && t < 96) {
            int tt = t - 64;
            float4 nf = *(const float4*)(emb + (size_t)drug[b] * DDIM + 4 * tt);
            *(float4*)(node_f + (size_t)b * DDIM + 4 * tt) = nf;
        }
        __syncthreads();
        const int r = t >> 4, g8 = t & 15;       // relation, 8-col (32 B) group
        const int n = sm.g.cnt[r];
        float acc[8] = {0.f, 0.f, 0.f, 0.f, 0.f, 0.f, 0.f, 0.f};
        for (int j = 0; j < n; ++j) {
            int s = sm.g.memb[r][j];
            float wq = sm.g.swt[s];
            const float* p = emb + (size_t)sm.g.sent[s] * DDIM + 8 * g8;
            float4 v0 = *(const float4*)p;
            float4 v1 = *(const float4*)(p + 4);
            acc[0] = fmaf(v0.x, wq, acc[0]); acc[1] = fmaf(v0.y, wq, acc[1]);
            acc[2] = fmaf(v0.z, wq, acc[2]); acc[3] = fmaf(v0.w, wq, acc[3]);
            acc[4] = fmaf(v1.x, wq, acc[4]); acc[5] = fmaf(v1.y, wq, acc[5]);
            acc[6] = fmaf(v1.z, wq, acc[6]); acc[7] = fmaf(v1.w, wq, acc[7]);
        }
        short8 o;
        #pragma unroll
        for (int jj = 0; jj < 8; ++jj) o[jj] = (short)f2bf(acc[jj]);
        *(short8*)(pre_bf + (size_t)b * 2048 + r * DDIM + 8 * g8) = o;
    } else if (bid < BBATCH + 128) {
        // ---------------- Wcat transpose: 64k x 64e tile ----------------
        const int bid2 = bid - BBATCH;
        const int l = bid2 >> 6, rem = bid2 & 63;
        const int k0 = (rem >> 1) * 64, e0 = (rem & 1) * 64;
        #pragma unroll
        for (int i = 0; i < 4; ++i) {
            int flat = t + 256 * i;              // 64 k x 16 col4
            int k = flat >> 4, c = flat & 15;
            float4 v = *(const float4*)(W_rgcn + ((size_t)(l * 2048 + k0 + k)) * 128 + e0 + 4 * c);
            sm.w.tileT[(4 * c + 0) * 65 + k] = v.x;
            sm.w.tileT[(4 * c + 1) * 65 + k] = v.y;
            sm.w.tileT[(4 * c + 2) * 65 + k] = v.z;
            sm.w.tileT[(4 * c + 3) * 65 + k] = v.w;
        }
        __syncthreads();
        const int e = t >> 2, m = t & 3;
        #pragma unroll
        for (int half = 0; half < 2; ++half) {
            int kk = 16 * m + 8 * half;
            short8 o;
            #pragma unroll
            for (int j = 0; j < 8; ++j) o[j] = (short)f2bf(sm.w.tileT[e * 65 + kk + j]);
            *(short8*)(Wcat + ((size_t)(l * 128 + e0 + e)) * 2048 + k0 + kk) = o;
        }
    } else {
        // ---------------- flat weight converts ----------------
        int j4 = ((bid - BBATCH - 128) * 256 + t) * 4;   // 131072 floats
        const float* src; unsigned short* dst; int off;
        if (j4 < 32768)       { src = res_w;  dst = resw;  off = j4; }
        else if (j4 < 65536)  { src = proj_w; dst = projw; off = j4 - 32768; }
        else if (j4 < 114688) { src = in_w;   dst = inw;   off = j4 - 65536; }
        else                  { src = out_w;  dst = outw;  off = j4 - 114688; }
        float4 v = *(const float4*)(src + off);
        ushort4 o = { f2bf(v.x), f2bf(v.y), f2bf(v.z), f2bf(v.w) };
        *(ushort4*)(dst + off) = o;
    }
}

// ============ tail: msgs GEMM + layers + attention + out; 16 rows, 512 thr (8 waves) ==
extern "C" __global__ __launch_bounds__(512)
void k_tail(const unsigned short* __restrict__ pre_bf, const unsigned short* __restrict__ Wcat,
            const float* __restrict__ node_fg,
            const unsigned short* __restrict__ resw, const unsigned short* __restrict__ projw,
            const float* __restrict__ res_b, const float* __restrict__ proj_b,
            const float* __restrict__ ln_g, const float* __restrict__ ln_b,
            const unsigned short* __restrict__ inw, const float* __restrict__ in_b,
            const unsigned short* __restrict__ outw, const float* __restrict__ out_b,
            const float* __restrict__ fg, const float* __restrict__ fb,
            float* __restrict__ outp)
{
    __shared__ float          node_ln[16 * 132];
    __shared__ unsigned short node_b16[16 * 136];
    __shared__ unsigned short h_b16[16 * 136];
    __shared__ float          msum[16 * 260];
    __shared__ unsigned short xs_l[32 * 136];
    __shared__ unsigned short qkvl[32 * 392];
    __shared__ float          psum[8][16], psq[8][16];

    const int t = threadIdx.x, w = t >> 6, lane = t & 63, l15 = lane & 15, q = lane >> 4;
    const int r0 = blockIdx.x * 16;

    // ---- stage 0a: node rows into LDS (512 threads = 16 rows x 32 col4 exactly) ----
    {
        int rr = t >> 5, c = t & 31;
        float4 v = *(const float4*)(node_fg + (size_t)(r0 + rr) * DDIM + 4 * c);
        *(float4*)(node_ln + rr * 132 + 4 * c) = v;
        ushort4 o = { f2bf(v.x), f2bf(v.y), f2bf(v.z), f2bf(v.w) };
        *(ushort4*)(node_b16 + rr * 136 + 4 * c) = o;
    }

    // ---- stage 0b: msgs = pre[16,2048] x Wcat^T[2048,256]; wave w owns 32 cols ----
    {
        floatx4 macc[2] = {};
        const unsigned short* ap = pre_bf + (size_t)(r0 + l15) * 2048 + 8 * q;
        const unsigned short* bp = Wcat + (size_t)(32 * w + l15) * 2048 + 8 * q;
        #pragma unroll 2
        for (int k = 0; k < 2048; k += 32) {
            short8 A = *(const short8*)(ap + k);
            short8 B0 = *(const short8*)(bp + k);
            short8 B1 = *(const short8*)(bp + (size_t)16 * 2048 + k);
            macc[0] = __builtin_amdgcn_mfma_f32_16x16x32_bf16(A, B0, macc[0], 0, 0, 0);
            macc[1] = __builtin_amdgcn_mfma_f32_16x16x32_bf16(A, B1, macc[1], 0, 0, 0);
        }
        #pragma unroll
        for (int ni = 0; ni < 2; ++ni) {
            int gc = 32 * w + ni * 16 + l15;
            #pragma unroll
            for (int r = 0; r < 4; ++r)
                msum[(4 * q + r) * 260 + gc] = macc[ni][r];
        }
    }
    __syncthreads();

    // ---- RGCN layers: wave w owns cols 16w..16w+15 for all 16 rows ----
    for (int l = 0; l < 2; ++l) {
        {   // GEMM1: h = relu(node + msum_l + node x resw_l^T + res_b)
            const unsigned short* Bw = resw + (size_t)l * DDIM * DDIM;
            floatx4 acc = {};
            const unsigned short* ap = node_b16 + l15 * 136 + 8 * q;
            #pragma unroll
            for (int kk = 0; kk < DDIM; kk += 32) {
                short8 A = *(const short8*)(ap + kk);
                short8 B = *(const short8*)(Bw + (size_t)(16 * w + l15) * DDIM + kk + 8 * q);
                acc = __builtin_amdgcn_mfma_f32_16x16x32_bf16(A, B, acc, 0, 0, 0);
            }
            int gc = 16 * w + l15;
            float rb = res_b[l * DDIM + gc];
            #pragma unroll
            for (int r = 0; r < 4; ++r) {
                int lr = 4 * q + r;
                float v = acc[r] + rb + node_ln[lr * 132 + gc] + msum[lr * 260 + l * DDIM + gc];
                h_b16[lr * 136 + gc] = f2bf(v > 0.f ? v : 0.f);
            }
        }
        __syncthreads();
        {   // GEMM2 + LN
            const unsigned short* Bw = projw + (size_t)l * DDIM * DDIM;
            floatx4 acc = {};
            const unsigned short* ap = h_b16 + l15 * 136 + 8 * q;
            #pragma unroll
            for (int kk = 0; kk < DDIM; kk += 32) {
                short8 A = *(const short8*)(ap + kk);
                short8 B = *(const short8*)(Bw + (size_t)(16 * w + l15) * DDIM + kk + 8 * q);
                acc = __builtin_amdgcn_mfma_f32_16x16x32_bf16(A, B, acc, 0, 0, 0);
            }
            int gc = 16 * w + l15;
            float vv[4];
            float s4[4], sq4[4];
            float pb = proj_b[l * DDIM + gc];
            #pragma unroll
            for (int r = 0; r < 4; ++r) {
                int lr = 4 * q + r;
                float v = acc[r] + pb + node_ln[lr * 132 + gc];
                vv[r] = v; s4[r] = v; sq4[r] = v * v;
            }
            #pragma unroll
            for (int r = 0; r < 4; ++r)
                #pragma unroll
                for (int off2 = 8; off2 >= 1; off2 >>= 1) {
                    s4[r] += __shfl_xor(s4[r], off2, 64);
                    sq4[r] += __shfl_xor(sq4[r], off2, 64);
                }
            if (l15 == 0) {
                #pragma unroll
                for (int r = 0; r < 4; ++r) {
                    psum[w][4 * q + r] = s4[r];
                    psq[w][4 * q + r] = sq4[r];
                }
            }
            __syncthreads();
            float g2 = ln_g[l * DDIM + gc], bb = ln_b[l * DDIM + gc];
            #pragma unroll
            for (int r = 0; r < 4; ++r) {
                int lr = 4 * q + r;
                float ssum = 0.f, ssq = 0.f;
                #pragma unroll
                for (int ww = 0; ww < 8; ++ww) { ssum += psum[ww][lr]; ssq += psq[ww][lr]; }
                float mean = ssum * (1.f / DDIM);
                float var = ssq * (1.f / DDIM) - mean * mean;
                float val = (vv[r] - mean) * rsqrtf(var + 1e-5f) * g2 + bb;
                node_ln[lr * 132 + gc] = val;
                unsigned short ub = f2bf(val);
                node_b16[lr * 136 + gc] = ub;
                xs_l[(2 * lr + l) * 136 + gc] = ub;
            }
            __syncthreads();
        }
    }

    // ---- qkv: wave w -> xs rows 16*(w&1).., cols 96*(w>>1).. ----
    {
        floatx4 acc[6] = {};
        const unsigned short* ap = xs_l + (16 * (w & 1) + l15) * 136 + 8 * q;
        #pragma unroll
        for (int kk = 0; kk < DDIM; kk += 32) {
            short8 A = *(const short8*)(ap + kk);
            #pragma unroll
            for (int ni = 0; ni < 6; ++ni) {
                short8 B = *(const short8*)(inw + (size_t)(96 * (w >> 1) + ni * 16 + l15) * DDIM + kk + 8 * q);
                acc[ni] = __builtin_amdgcn_mfma_f32_16x16x32_bf16(A, B, acc[ni], 0, 0, 0);
            }
        }
        #pragma unroll
        for (int ni = 0; ni < 6; ++ni) {
            int gc = 96 * (w >> 1) + ni * 16 + l15;
            float ib = in_b[gc];
            #pragma unroll
            for (int r = 0; r < 4; ++r)
                qkvl[(16 * (w & 1) + 4 * q + r) * 392 + gc] = f2bf(acc[ni][r] + ib);
        }
    }
    __syncthreads();

    // ---- attention: 16 batch rows x 8 lanes (t < 128) ----
    if (t < 128) {
        int g4 = t >> 3, j = t & 7;
        const unsigned short* row0 = qkvl + (2 * g4) * 392;
        const unsigned short* row1 = row0 + 392;
        float p00 = 0.f, p01 = 0.f, p10 = 0.f, p11 = 0.f;
        #pragma unroll
        for (int dd = 0; dd < 16; ++dd) {
            int d = 16 * j + dd;
            float q0 = bf2f(row0[d]), k0 = bf2f(row0[128 + d]);
            float q1 = bf2f(row1[d]), k1 = bf2f(row1[128 + d]);
            p00 = fmaf(q0, k0, p00); p01 = fmaf(q0, k1, p01);
            p10 = fmaf(q1, k0, p10); p11 = fmaf(q1, k1, p11);
        }
        p00 += __shfl_xor(p00, 1, 64); p01 += __shfl_xor(p01, 1, 64);
        p10 += __shfl_xor(p10, 1, 64); p11 += __shfl_xor(p11, 1, 64);
        const float sc = 0.17677669529663687f;   // 1/sqrt(32)
        p00 *= sc; p01 *= sc; p10 *= sc; p11 *= sc;
        float m0 = fmaxf(p00, p01), e00 = expf(p00 - m0), e01 = expf(p01 - m0);
        float i0 = 1.f / (e00 + e01);
        float m1 = fmaxf(p10, p11), e10 = expf(p10 - m1), e11 = expf(p11 - m1);
        float i1 = 1.f / (e10 + e11);
        #pragma unroll
        for (int dd = 0; dd < 16; ++dd) {
            int d = 16 * j + dd;
            float v0 = bf2f(row0[256 + d]), v1 = bf2f(row1[256 + d]);
            xs_l[(2 * g4) * 136 + d]     = f2bf((e00 * v0 + e01 * v1) * i0);
            xs_l[(2 * g4 + 1) * 136 + d] = f2bf((e10 * v0 + e11 * v1) * i1);
        }
    }
    __syncthreads();

    // ---- out-proj + mean over L + final LN: wave w -> o rows 16*(w&1), cols 32*(w>>1) --
    {
        floatx4 acc[2] = {};
        const unsigned short* ap = xs_l + (16 * (w & 1) + l15) * 136 + 8 * q;
        #pragma unroll
        for (int kk = 0; kk < DDIM; kk += 32) {
            short8 A = *(const short8*)(ap + kk);
            #pragma unroll
            for (int ni = 0; ni < 2; ++ni) {
                short8 B = *(const short8*)(outw + (size_t)(32 * (w >> 1) + ni * 16 + l15) * DDIM + kk + 8 * q);
                acc[ni] = __builtin_amdgcn_mfma_f32_16x16x32_bf16(A, B, acc[ni], 0, 0, 0);
            }
        }
        float av[2][2];
        float s2[2] = {0, 0}, sq2[2] = {0, 0};
        #pragma unroll
        for (int ni = 0; ni < 2; ++ni) {
            int gc = 32 * (w >> 1) + ni * 16 + l15;
            float ob = out_b[gc];
            #pragma unroll
            for (int rr = 0; rr < 2; ++rr) {
                float v = 0.5f * (acc[ni][2 * rr] + acc[ni][2 * rr + 1]) + ob;
                av[ni][rr] = v; s2[rr] += v; sq2[rr] += v * v;
            }
        }
        #pragma unroll
        for (int rr = 0; rr < 2; ++rr)
            #pragma unroll
            for (int off2 = 8; off2 >= 1; off2 >>= 1) {
                s2[rr] += __shfl_xor(s2[rr], off2, 64);
                sq2[rr] += __shfl_xor(sq2[rr], off2, 64);
            }
        if (l15 == 0) {
            #pragma unroll
            for (int rr = 0; rr < 2; ++rr) {
                psum[w][2 * q + rr] = s2[rr];
                psq[w][2 * q + rr] = sq2[rr];
            }
        }
        __syncthreads();
        #pragma unroll
        for (int ni = 0; ni < 2; ++ni) {
            int gc = 32 * (w >> 1) + ni * 16 + l15;
            float g2 = fg[gc], bb = fb[gc];
            #pragma unroll
            for (int rr = 0; rr < 2; ++rr) {
                int idx = 2 * q + rr;
                int bl = 8 * (w & 1) + idx;
                float ssum = psum[w & 1][idx] + psum[(w & 1) + 2][idx]
                           + psum[(w & 1) + 4][idx] + psum[(w & 1) + 6][idx];
                float ssq  = psq[w & 1][idx] + psq[(w & 1) + 2][idx]
                           + psq[(w & 1) + 4][idx] + psq[(w & 1) + 6][idx];
                float mean = ssum * (1.f / DDIM);
                float var = ssq * (1.f / DDIM) - mean * mean;
                outp[(size_t)(r0 + bl) * DDIM + gc] = (av[ni][rr] - mean) * rsqrtf(var + 1e-5f) * g2 + bb;
            }
        }
    }
}

extern "C" void kernel_launch(void* const* d_in, const int* in_sizes, int n_in,
                              void* d_out, int out_size, void* d_ws, size_t ws_size,
                              hipStream_t stream) {
    const int*   drug_idx = (const int*)d_in[0];
    const int*   adj_ent  = (const int*)d_in[1];
    const int*   adj_rel  = (const int*)d_in[2];
    const float* ew       = (const float*)d_in[3];
    const float* emb      = (const float*)d_in[4];
    const float* W_rgcn   = (const float*)d_in[5];
    const float* res_w    = (const float*)d_in[6];
    const float* res_b    = (const float*)d_in[7];
    const float* proj_w   = (const float*)d_in[8];
    const float* proj_b   = (const float*)d_in[9];
    const float* ln_g     = (const float*)d_in[10];
    const float* ln_b     = (const float*)d_in[11];
    const float* in_w     = (const float*)d_in[12];
    const float* in_b     = (const float*)d_in[13];
    const float* out_w    = (const float*)d_in[14];
    const float* out_b    = (const float*)d_in[15];
    const float* fg       = (const float*)d_in[16];
    const float* fb       = (const float*)d_in[17];
    float* outp = (float*)d_out;

    char* ws = (char*)d_ws;
    size_t off = 0;
    auto alloc = [&](size_t bytes) { size_t o = off; off = (off + bytes + 255) & ~(size_t)255; return o; };
    unsigned short* pre_bf  = (unsigned short*)(ws + alloc((size_t)BBATCH * 2048 * 2));
    float*          node_f  = (float*)         (ws + alloc((size_t)BBATCH * 128 * 4));
    unsigned short* Wcat    = (unsigned short*)(ws + alloc((size_t)256 * 2048 * 2));
    unsigned short* resw    = (unsigned short*)(ws + alloc((size_t)2 * 128 * 128 * 2));
    unsigned short* projw   = (unsigned short*)(ws + alloc((size_t)2 * 128 * 128 * 2));
    unsigned short* inw     = (unsigned short*)(ws + alloc((size_t)384 * 128 * 2));
    unsigned short* outw    = (unsigned short*)(ws + alloc((size_t)128 * 128 * 2));

    hipLaunchKernelGGL(k_front, dim3(BBATCH + 256), dim3(256), 0, stream,
                       drug_idx, adj_ent, adj_rel, ew, emb, W_rgcn,
                       res_w, proj_w, in_w, out_w,
                       pre_bf, node_f, Wcat, resw, projw, inw, outw);
    hipLaunchKernelGGL(k_tail, dim3(256), dim3(512), 0, stream,
                       pre_bf, Wcat, node_f, resw, projw, res_b, proj_b, ln_g, ln_b,
                       inw, in_b, outw, out_b, fg, fb, outp);
}

// Round 9
// 240.236 us; speedup vs baseline: 1.0448x; 1.0448x over previous
//
#include <hip/hip_runtime.h>
#include <math.h>

#define NRREL 16
#define DDIM 128
#define BBATCH 4096
#define SNBR 64

typedef __attribute__((ext_vector_type(8))) short short8;
typedef __attribute__((ext_vector_type(4))) float floatx4;

__device__ __forceinline__ unsigned short f2bf(float f) {
    unsigned u = __builtin_bit_cast(unsigned, f);
    u += 0x7fffu + ((u >> 16) & 1u);
    return (unsigned short)(u >> 16);
}
__device__ __forceinline__ float bf2f(unsigned short u) {
    return __builtin_bit_cast(float, ((unsigned)u) << 16);
}

// ============ front: gather (blocks 0..4095) + weight conversion (4096..4351) =========
extern "C" __global__ __launch_bounds__(256)
void k_front(const int* __restrict__ drug, const int* __restrict__ adj_e,
             const int* __restrict__ adj_r, const float* __restrict__ ew,
             const float* __restrict__ emb, const float* __restrict__ W_rgcn,
             const float* __restrict__ res_w, const float* __restrict__ proj_w,
             const float* __restrict__ in_w, const float* __restrict__ out_w,
             unsigned short* __restrict__ pre_bf, float* __restrict__ node_f,
             unsigned short* __restrict__ Wcat, unsigned short* __restrict__ resw,
             unsigned short* __restrict__ projw, unsigned short* __restrict__ inw,
             unsigned short* __restrict__ outw)
{
    __shared__ union {
        struct {
            int memb[16][64];                   // relation bucket member lists
            int cnt[16];
            int sent[64];
            float swt[64];
        } g;
        struct { float tileT[64 * 65]; } w;
    } sm;

    const int bid = blockIdx.x, t = threadIdx.x;

    if (bid < BBATCH) {
        // ---------------- gather one batch row: direct global->register ----------------
        const int b = bid;
        if (t < 16) sm.g.cnt[t] = 0;
        __syncthreads();
        if (t < 64) {
            sm.g.sent[t] = adj_e[b * SNBR + t];
            sm.g.swt[t]  = ew[b * SNBR + t];
            int r = adj_r[b * SNBR + t];
            int slot = atomicAdd(&sm.g.cnt[r], 1);
            sm.g.memb[r][slot] = t;
        }
        if (t >= 64 && t < 96) {
            int tt = t - 64;
            float4 nf = *(const float4*)(emb + (size_t)drug[b] * DDIM + 4 * tt);
            *(float4*)(node_f + (size_t)b * DDIM + 4 * tt) = nf;
        }
        __syncthreads();
        const int r = t >> 4, g8 = t & 15;       // relation, 8-col (32 B) group
        const int n = sm.g.cnt[r];
        float acc[8] = {0.f, 0.f, 0.f, 0.f, 0.f, 0.f, 0.f, 0.f};
        for (int j = 0; j < n; ++j) {
            int s = sm.g.memb[r][j];
            float wq = sm.g.swt[s];
            const float* p = emb + (size_t)sm.g.sent[s] * DDIM + 8 * g8;
            float4 v0 = *(const float4*)p;
            float4 v1 = *(const float4*)(p + 4);
            acc[0] = fmaf(v0.x, wq, acc[0]); acc[1] = fmaf(v0.y, wq, acc[1]);
            acc[2] = fmaf(v0.z, wq, acc[2]); acc[3] = fmaf(v0.w, wq, acc[3]);
            acc[4] = fmaf(v1.x, wq, acc[4]); acc[5] = fmaf(v1.y, wq, acc[5]);
            acc[6] = fmaf(v1.z, wq, acc[6]); acc[7] = fmaf(v1.w, wq, acc[7]);
        }
        short8 o;
        #pragma unroll
        for (int jj = 0; jj < 8; ++jj) o[jj] = (short)f2bf(acc[jj]);
        *(short8*)(pre_bf + (size_t)b * 2048 + r * DDIM + 8 * g8) = o;
    } else if (bid < BBATCH + 128) {
        // ---------------- Wcat transpose: 64k x 64e tile ----------------
        const int bid2 = bid - BBATCH;
        const int l = bid2 >> 6, rem = bid2 & 63;
        const int k0 = (rem >> 1) * 64, e0 = (rem & 1) * 64;
        #pragma unroll
        for (int i = 0; i < 4; ++i) {
            int flat = t + 256 * i;              // 64 k x 16 col4
            int k = flat >> 4, c = flat & 15;
            float4 v = *(const float4*)(W_rgcn + ((size_t)(l * 2048 + k0 + k)) * 128 + e0 + 4 * c);
            sm.w.tileT[(4 * c + 0) * 65 + k] = v.x;
            sm.w.tileT[(4 * c + 1) * 65 + k] = v.y;
            sm.w.tileT[(4 * c + 2) * 65 + k] = v.z;
            sm.w.tileT[(4 * c + 3) * 65 + k] = v.w;
        }
        __syncthreads();
        const int e = t >> 2, m = t & 3;
        #pragma unroll
        for (int half = 0; half < 2; ++half) {
            int kk = 16 * m + 8 * half;
            short8 o;
            #pragma unroll
            for (int j = 0; j < 8; ++j) o[j] = (short)f2bf(sm.w.tileT[e * 65 + kk + j]);
            *(short8*)(Wcat + ((size_t)(l * 128 + e0 + e)) * 2048 + k0 + kk) = o;
        }
    } else {
        // ---------------- flat weight converts ----------------
        int j4 = ((bid - BBATCH - 128) * 256 + t) * 4;   // 131072 floats
        const float* src; unsigned short* dst; int off;
        if (j4 < 32768)       { src = res_w;  dst = resw;  off = j4; }
        else if (j4 < 65536)  { src = proj_w; dst = projw; off = j4 - 32768; }
        else if (j4 < 114688) { src = in_w;   dst = inw;   off = j4 - 65536; }
        else                  { src = out_w;  dst = outw;  off = j4 - 114688; }
        float4 v = *(const float4*)(src + off);
        ushort4 o = { f2bf(v.x), f2bf(v.y), f2bf(v.z), f2bf(v.w) };
        *(ushort4*)(dst + off) = o;
    }
}

// ============ tail: A-staged msgs GEMM + layers + attention + out; 256 thr, 16 rows ===
extern "C" __global__ __launch_bounds__(256)
void k_tail(const unsigned short* __restrict__ pre_bf, const unsigned short* __restrict__ Wcat,
            const float* __restrict__ node_fg,
            const unsigned short* __restrict__ resw, const unsigned short* __restrict__ projw,
            const float* __restrict__ res_b, const float* __restrict__ proj_b,
            const float* __restrict__ ln_g, const float* __restrict__ ln_b,
            const unsigned short* __restrict__ inw, const float* __restrict__ in_b,
            const unsigned short* __restrict__ outw, const float* __restrict__ out_b,
            const float* __restrict__ fg, const float* __restrict__ fb,
            float* __restrict__ outp)
{
    __shared__ union {
        struct { unsigned short preA[16 * 2056]; } a;     // 65.8 KB: msgs-phase A stage
        struct {
            float          node_ln[16 * 132];
            unsigned short node_b16[16 * 136];
            unsigned short h_b16[16 * 136];
            unsigned short xs_l[32 * 136];
            unsigned short qkvl[32 * 392];
        } t;
    } sm;
    __shared__ float msum[16 * 260];
    __shared__ float psum[4][16], psq[4][16];

    const int t = threadIdx.x, w = t >> 6, lane = t & 63, l15 = lane & 15, q = lane >> 4;
    const int r0 = blockIdx.x * 16;

    // ---- stage A: burst-load 16 pre rows (64 KB) into LDS; 16 independent 16B loads --
    #pragma unroll
    for (int i = 0; i < 16; ++i) {
        short8 v = *(const short8*)(pre_bf + (size_t)(r0 + i) * 2048 + 8 * t);
        *(short8*)(sm.a.preA + i * 2056 + 8 * t) = v;
    }
    __syncthreads();

    // ---- msgs = preA[16,2048] x Wcat^T[2048,256]; wave w owns 64 cols ----
    {
        floatx4 macc[4] = {};
        const unsigned short* ap = sm.a.preA + l15 * 2056 + 8 * q;
        const unsigned short* bp = Wcat + (size_t)(64 * w + l15) * 2048 + 8 * q;
        #pragma unroll 4
        for (int k = 0; k < 2048; k += 32) {
            short8 A = *(const short8*)(ap + k);
            #pragma unroll
            for (int ni = 0; ni < 4; ++ni) {
                short8 B = *(const short8*)(bp + (size_t)(ni * 16) * 2048 + k);
                macc[ni] = __builtin_amdgcn_mfma_f32_16x16x32_bf16(A, B, macc[ni], 0, 0, 0);
            }
        }
        #pragma unroll
        for (int ni = 0; ni < 4; ++ni) {
            int gc = 64 * w + ni * 16 + l15;
            #pragma unroll
            for (int r = 0; r < 4; ++r)
                msum[(4 * q + r) * 260 + gc] = macc[ni][r];
        }
    }
    __syncthreads();          // preA dead; sm.t alive from here

    // ---- node rows into LDS ----
    #pragma unroll
    for (int i = 0; i < 2; ++i) {
        int flat = t + 256 * i;                  // 16 rows x 32 col4
        int rr = flat >> 5, c = flat & 31;
        float4 v = *(const float4*)(node_fg + (size_t)(r0 + rr) * DDIM + 4 * c);
        *(float4*)(sm.t.node_ln + rr * 132 + 4 * c) = v;
        ushort4 o = { f2bf(v.x), f2bf(v.y), f2bf(v.z), f2bf(v.w) };
        *(ushort4*)(sm.t.node_b16 + rr * 136 + 4 * c) = o;
    }
    __syncthreads();

    // ---- RGCN layers: wave w owns cols 32w..32w+31 for all 16 rows ----
    for (int l = 0; l < 2; ++l) {
        {   // GEMM1: h = relu(node + msum_l + node x resw_l^T + res_b)
            const unsigned short* Bw = resw + (size_t)l * DDIM * DDIM;
            floatx4 acc[2] = {};
            const unsigned short* ap = sm.t.node_b16 + l15 * 136 + 8 * q;
            #pragma unroll
            for (int kk = 0; kk < DDIM; kk += 32) {
                short8 A = *(const short8*)(ap + kk);
                #pragma unroll
                for (int ni = 0; ni < 2; ++ni) {
                    short8 B = *(const short8*)(Bw + (size_t)(32 * w + ni * 16 + l15) * DDIM + kk + 8 * q);
                    acc[ni] = __builtin_amdgcn_mfma_f32_16x16x32_bf16(A, B, acc[ni], 0, 0, 0);
                }
            }
            #pragma unroll
            for (int ni = 0; ni < 2; ++ni) {
                int gc = 32 * w + ni * 16 + l15;
                float rb = res_b[l * DDIM + gc];
                #pragma unroll
                for (int r = 0; r < 4; ++r) {
                    int lr = 4 * q + r;
                    float v = acc[ni][r] + rb + sm.t.node_ln[lr * 132 + gc] + msum[lr * 260 + l * DDIM + gc];
                    sm.t.h_b16[lr * 136 + gc] = f2bf(v > 0.f ? v : 0.f);
                }
            }
        }
        __syncthreads();
        {   // GEMM2 + LN
            const unsigned short* Bw = projw + (size_t)l * DDIM * DDIM;
            floatx4 acc[2] = {};
            const unsigned short* ap = sm.t.h_b16 + l15 * 136 + 8 * q;
            #pragma unroll
            for (int kk = 0; kk < DDIM; kk += 32) {
                short8 A = *(const short8*)(ap + kk);
                #pragma unroll
                for (int ni = 0; ni < 2; ++ni) {
                    short8 B = *(const short8*)(Bw + (size_t)(32 * w + ni * 16 + l15) * DDIM + kk + 8 * q);
                    acc[ni] = __builtin_amdgcn_mfma_f32_16x16x32_bf16(A, B, acc[ni], 0, 0, 0);
                }
            }
            float vv[2][4];
            float s4[4] = {0, 0, 0, 0}, sq4[4] = {0, 0, 0, 0};
            #pragma unroll
            for (int ni = 0; ni < 2; ++ni) {
                int gc = 32 * w + ni * 16 + l15;
                float pb = proj_b[l * DDIM + gc];
                #pragma unroll
                for (int r = 0; r < 4; ++r) {
                    int lr = 4 * q + r;
                    float v = acc[ni][r] + pb + sm.t.node_ln[lr * 132 + gc];
                    vv[ni][r] = v; s4[r] += v; sq4[r] += v * v;
                }
            }
            #pragma unroll
            for (int r = 0; r < 4; ++r)
                #pragma unroll
                for (int off2 = 8; off2 >= 1; off2 >>= 1) {
                    s4[r] += __shfl_xor(s4[r], off2, 64);
                    sq4[r] += __shfl_xor(sq4[r], off2, 64);
                }
            if (l15 == 0) {
                #pragma unroll
                for (int r = 0; r < 4; ++r) {
                    psum[w][4 * q + r] = s4[r];
                    psq[w][4 * q + r] = sq4[r];
                }
            }
            __syncthreads();
            #pragma unroll
            for (int ni = 0; ni < 2; ++ni) {
                int gc = 32 * w + ni * 16 + l15;
                float g2 = ln_g[l * DDIM + gc], bb = ln_b[l * DDIM + gc];
                #pragma unroll
                for (int r = 0; r < 4; ++r) {
                    int lr = 4 * q + r;
                    float ssum = psum[0][lr] + psum[1][lr] + psum[2][lr] + psum[3][lr];
                    float ssq  = psq[0][lr] + psq[1][lr] + psq[2][lr] + psq[3][lr];
                    float mean = ssum * (1.f / DDIM);
                    float var = ssq * (1.f / DDIM) - mean * mean;
                    float val = (vv[ni][r] - mean) * rsqrtf(var + 1e-5f) * g2 + bb;
                    sm.t.node_ln[lr * 132 + gc] = val;
                    unsigned short ub = f2bf(val);
                    sm.t.node_b16[lr * 136 + gc] = ub;
                    sm.t.xs_l[(2 * lr + l) * 136 + gc] = ub;
                }
            }
            __syncthreads();
        }
    }

    // ---- qkv: wave w -> xs rows 16*(w&1).., cols 192*(w>>1).. ----
    {
        floatx4 acc[12] = {};
        const unsigned short* ap = sm.t.xs_l + (16 * (w & 1) + l15) * 136 + 8 * q;
        #pragma unroll
        for (int kk = 0; kk < DDIM; kk += 32) {
            short8 A = *(const short8*)(ap + kk);
            #pragma unroll
            for (int ni = 0; ni < 12; ++ni) {
                short8 B = *(const short8*)(inw + (size_t)(192 * (w >> 1) + ni * 16 + l15) * DDIM + kk + 8 * q);
                acc[ni] = __builtin_amdgcn_mfma_f32_16x16x32_bf16(A, B, acc[ni], 0, 0, 0);
            }
        }
        #pragma unroll
        for (int ni = 0; ni < 12; ++ni) {
            int gc = 192 * (w >> 1) + ni * 16 + l15;
            float ib = in_b[gc];
            #pragma unroll
            for (int r = 0; r < 4; ++r)
                sm.t.qkvl[(16 * (w & 1) + 4 * q + r) * 392 + gc] = f2bf(acc[ni][r] + ib);
        }
    }
    __syncthreads();

    // ---- attention: 16 batch rows x 8 lanes (t < 128) ----
    if (t < 128) {
        int g4 = t >> 3, j = t & 7;
        const unsigned short* row0 = sm.t.qkvl + (2 * g4) * 392;
        const unsigned short* row1 = row0 + 392;
        float p00 = 0.f, p01 = 0.f, p10 = 0.f, p11 = 0.f;
        #pragma unroll
        for (int dd = 0; dd < 16; ++dd) {
            int d = 16 * j + dd;
            float q0 = bf2f(row0[d]), k0 = bf2f(row0[128 + d]);
            float q1 = bf2f(row1[d]), k1 = bf2f(row1[128 + d]);
            p00 = fmaf(q0, k0, p00); p01 = fmaf(q0, k1, p01);
            p10 = fmaf(q1, k0, p10); p11 = fmaf(q1, k1, p11);
        }
        p00 += __shfl_xor(p00, 1, 64); p01 += __shfl_xor(p01, 1, 64);
        p10 += __shfl_xor(p10, 1, 64); p11 += __shfl_xor(p11, 1, 64);
        const float sc = 0.17677669529663687f;   // 1/sqrt(32)
        p00 *= sc; p01 *= sc; p10 *= sc; p11 *= sc;
        float m0 = fmaxf(p00, p01), e00 = expf(p00 - m0), e01 = expf(p01 - m0);
        float i0 = 1.f / (e00 + e01);
        float m1 = fmaxf(p10, p11), e10 = expf(p10 - m1), e11 = expf(p11 - m1);
        float i1 = 1.f / (e10 + e11);
        #pragma unroll
        for (int dd = 0; dd < 16; ++dd) {
            int d = 16 * j + dd;
            float v0 = bf2f(row0[256 + d]), v1 = bf2f(row1[256 + d]);
            sm.t.xs_l[(2 * g4) * 136 + d]     = f2bf((e00 * v0 + e01 * v1) * i0);
            sm.t.xs_l[(2 * g4 + 1) * 136 + d] = f2bf((e10 * v0 + e11 * v1) * i1);
        }
    }
    __syncthreads();

    // ---- out-proj + mean over L + final LN: wave w -> o rows 16*(w&1), cols 64*(w>>1) --
    {
        floatx4 acc[4] = {};
        const unsigned short* ap = sm.t.xs_l + (16 * (w & 1) + l15) * 136 + 8 * q;
        #pragma unroll
        for (int kk = 0; kk < DDIM; kk += 32) {
            short8 A = *(const short8*)(ap + kk);
            #pragma unroll
            for (int ni = 0; ni < 4; ++ni) {
                short8 B = *(const short8*)(outw + (size_t)(64 * (w >> 1) + ni * 16 + l15) * DDIM + kk + 8 * q);
                acc[ni] = __builtin_amdgcn_mfma_f32_16x16x32_bf16(A, B, acc[ni], 0, 0, 0);
            }
        }
        float av[4][2];
        float s2[2] = {0, 0}, sq2[2] = {0, 0};
        #pragma unroll
        for (int ni = 0; ni < 4; ++ni) {
            int gc = 64 * (w >> 1) + ni * 16 + l15;
            float ob = out_b[gc];
            #pragma unroll
            for (int rr = 0; rr < 2; ++rr) {
                float v = 0.5f * (acc[ni][2 * rr] + acc[ni][2 * rr + 1]) + ob;
                av[ni][rr] = v; s2[rr] += v; sq2[rr] += v * v;
            }
        }
        #pragma unroll
        for (int rr = 0; rr < 2; ++rr)
            #pragma unroll
            for (int off2 = 8; off2 >= 1; off2 >>= 1) {
                s2[rr] += __shfl_xor(s2[rr], off2, 64);
                sq2[rr] += __shfl_xor(sq2[rr], off2, 64);
            }
        if (l15 == 0) {
            #pragma unroll
            for (int rr = 0; rr < 2; ++rr) {
                psum[w][2 * q + rr] = s2[rr];
                psq[w][2 * q + rr] = sq2[rr];
            }
        }
        __syncthreads();
        #pragma unroll
        for (int ni = 0; ni < 4; ++ni) {
            int gc = 64 * (w >> 1) + ni * 16 + l15;
            float g2 = fg[gc], bb = fb[gc];
            #pragma unroll
            for (int rr = 0; rr < 2; ++rr) {
                int idx = 2 * q + rr;
                int bl = 8 * (w & 1) + idx;
                float ssum = psum[w & 1][idx] + psum[(w & 1) + 2][idx];
                float ssq  = psq[w & 1][idx] + psq[(w & 1) + 2][idx];
                float mean = ssum * (1.f / DDIM);
                float var = ssq * (1.f / DDIM) - mean * mean;
                outp[(size_t)(r0 + bl) * DDIM + gc] = (av[ni][rr] - mean) * rsqrtf(var + 1e-5f) * g2 + bb;
            }
        }
    }
}

extern "C" void kernel_launch(void* const* d_in, const int* in_sizes, int n_in,
                              void* d_out, int out_size, void* d_ws, size_t ws_size,
                              hipStream_t stream) {
    const int*   drug_idx = (const int*)d_in[0];
    const int*   adj_ent  = (const int*)d_in[1];
    const int*   adj_rel  = (const int*)d_in[2];
    const float* ew       = (const float*)d_in[3];
    const float* emb      = (const float*)d_in[4];
    const float* W_rgcn   = (const float*)d_in[5];
    const float* res_w    = (const float*)d_in[6];
    const float* res_b    = (const float*)d_in[7];
    const float* proj_w   = (const float*)d_in[8];
    const float* proj_b   = (const float*)d_in[9];
    const float* ln_g     = (const float*)d_in[10];
    const float* ln_b     = (const float*)d_in[11];
    const float* in_w     = (const float*)d_in[12];
    const float* in_b     = (const float*)d_in[13];
    const float* out_w    = (const float*)d_in[14];
    const float* out_b    = (const float*)d_in[15];
    const float* fg       = (const float*)d_in[16];
    const float* fb       = (const float*)d_in[17];
    float* outp = (float*)d_out;

    char* ws = (char*)d_ws;
    size_t off = 0;
    auto alloc = [&](size_t bytes) { size_t o = off; off = (off + bytes + 255) & ~(size_t)255; return o; };
    unsigned short* pre_bf  = (unsigned short*)(ws + alloc((size_t)BBATCH * 2048 * 2));
    float*          node_f  = (float*)         (ws + alloc((size_t)BBATCH * 128 * 4));
    unsigned short* Wcat    = (unsigned short*)(ws + alloc((size_t)256 * 2048 * 2));
    unsigned short* resw    = (unsigned short*)(ws + alloc((size_t)2 * 128 * 128 * 2));
    unsigned short* projw   = (unsigned short*)(ws + alloc((size_t)2 * 128 * 128 * 2));
    unsigned short* inw     = (unsigned short*)(ws + alloc((size_t)384 * 128 * 2));
    unsigned short* outw    = (unsigned short*)(ws + alloc((size_t)128 * 128 * 2));

    hipLaunchKernelGGL(k_front, dim3(BBATCH + 256), dim3(256), 0, stream,
                       drug_idx, adj_ent, adj_rel, ew, emb, W_rgcn,
                       res_w, proj_w, in_w, out_w,
                       pre_bf, node_f, Wcat, resw, projw, inw, outw);
    hipLaunchKernelGGL(k_tail, dim3(256), dim3(256), 0, stream,
                       pre_bf, Wcat, node_f, resw, projw, res_b, proj_b, ln_g, ln_b,
                       inw, in_b, outw, out_b, fg, fb, outp);
}